// Round 1
// baseline (229.262 us; speedup 1.0000x reference)
//
#include <hip/hip_runtime.h>

// ---------------------------------------------------------------------------
// RoPE attention: out = softmax(mask(RoPE(xWq^T) @ RoPE(xWk^T)^T / sqrt(d))) @ (xWv^T)
// B=4, T=2048, d=1024. fp32 in/out, bf16 MFMA internally.
// R12 -> R13: pv_gemm CU-pairing balance. pv grid = 512 blocks, all
// co-resident at 2/CU. Dispatch maps block i and i+256 to the SAME CU
// (XCD round-robin i%8; 256/8=32 CU-slots). With linear idx = bn+8y+128z,
// i and i+256 share (bn,y) and differ by z+2 -> SAME bm -> same ktiles.
// Diagonal CUs carry 2x32=64 ktile-units vs 36 avg -> pv ~1.8x longer than
// balanced. Fix: z in {2,3} decodes bm ASCENDING so pair sums are
// ktiles(15-y)+ktiles(y) = 35..36 = const. Predicted pv ~0.6x, total ~205us.
// ---------------------------------------------------------------------------

typedef float f32x4 __attribute__((ext_vector_type(4)));
typedef __bf16 bf16x8 __attribute__((ext_vector_type(8)));

#define BM 128
#define BN 128
#define BK 64  // ushorts per LDS tile row; 128x64x2B = 16 KB per buffer

__device__ __forceinline__ unsigned short f2bf(float f) {
  union { float f; unsigned int u; } c; c.f = f;
  unsigned int u = c.u;
  u += 0x7fffu + ((u >> 16) & 1u);  // round-nearest-even
  return (unsigned short)(u >> 16);
}
__device__ __forceinline__ float bf2f(unsigned short h) {
  union { unsigned int u; float f; } c; c.u = ((unsigned int)h) << 16;
  return c.f;
}

__device__ __forceinline__ void async16(const unsigned short* gp, unsigned short* lp) {
  __builtin_amdgcn_global_load_lds(
      (const __attribute__((address_space(1))) void*)gp,
      (__attribute__((address_space(3))) void*)lp, 16, 0, 0);
}

// ---------------------------------------------------------------------------
// All fp32->bf16 casts in one kernel; last block zeroes rowsums.
__global__ __launch_bounds__(256) void cvt_all(
    const float4* __restrict__ x, const float4* __restrict__ wq,
    const float4* __restrict__ wk, const float4* __restrict__ wv,
    ushort4* __restrict__ xb, ushort4* __restrict__ wb,
    float4* __restrict__ rowsums) {
  int b = blockIdx.x, t = threadIdx.x;
  if (b == 11264) {  // zero rowsums: 4*2048 fp32 = 2048 float4
#pragma unroll
    for (int i = 0; i < 8; ++i) rowsums[i * 256 + t] = float4{0.f, 0.f, 0.f, 0.f};
    return;
  }
  const float4* src;
  ushort4* dst;
  long i;
  if (b < 8192) { src = x; dst = xb; i = (long)b * 256 + t; }
  else if (b < 9216) { src = wq; dst = wb; i = (long)(b - 8192) * 256 + t; }
  else if (b < 10240) { src = wk; dst = wb + 262144; i = (long)(b - 9216) * 256 + t; }
  else { src = wv; dst = wb + 524288; i = (long)(b - 10240) * 256 + t; }
  float4 v = src[i];
  ushort4 o;
  o.x = f2bf(v.x); o.y = f2bf(v.y); o.z = f2bf(v.z); o.w = f2bf(v.w);
  dst[i] = o;
}

// ---------------------------------------------------------------------------
// NT-GEMM K-loop, BK=64, single-buffer global_load_lds staging.
// C[m,n] = sum_k A[m,k]*B[n,k]. 128x128 tile, 4 waves (2x2), each 64x64 via
// 4x4 frags of mfma_f32_16x16x32_bf16, two k-steps of 32 per LDS tile.
// LDS position f=p*256+tid (16-B units) holds row=f>>3=p*32+srow; staged
// chunk c = (tid&7)^(srow&7) is p-invariant ((p*32)%8==0) -> two base
// pointers suffice, no per-p offset arrays. XOR swizzle keeps the DMA's
// lane-contiguous LDS layout conflict-free for frag reads (measured 0).
__device__ __forceinline__ void gemm_body(
    const unsigned short* __restrict__ A, const unsigned short* __restrict__ B,
    unsigned short* As, unsigned short* Bs,
    int lda, int ldb, int m0, int n0, int ktiles,
    int tid, int lane, int wave, f32x4 acc[4][4]) {
  const int wm = (wave >> 1) * 64;
  const int wn = (wave & 1) * 64;
  const int fm = lane & 15;
  const int q = lane >> 4;
  const int srow = tid >> 3;                 // 0..31
  const int c = (tid & 7) ^ (srow & 7);      // staged 16-B chunk (p-invariant)
  const unsigned short* Ab = A + (long)(m0 + srow) * lda + c * 8;
  const unsigned short* Bb = B + (long)(n0 + srow) * ldb + c * 8;
  unsigned short* ldA = As + tid * 8;
  unsigned short* ldB = Bs + tid * 8;

  for (int kt = 0; kt < ktiles; ++kt) {
    const long k0 = (long)kt * BK;
    __syncthreads();  // prior frag reads done before LDS overwrite
#pragma unroll
    for (int p = 0; p < 4; ++p) {
      async16(Ab + (long)(p * 32) * lda + k0, ldA + p * 2048);
      async16(Bb + (long)(p * 32) * ldb + k0, ldB + p * 2048);
    }
    __syncthreads();  // compiler drains vmcnt(0): tiles ready

#pragma unroll
    for (int s = 0; s < 2; ++s) {  // two k-steps of 32
      bf16x8 af[4], bfr[4];
#pragma unroll
      for (int i = 0; i < 4; ++i) {
        int row = wm + i * 16 + fm;
        af[i] = *(const bf16x8*)&As[row * 64 + ((((s << 2) | q) ^ (row & 7)) << 3)];
      }
#pragma unroll
      for (int j = 0; j < 4; ++j) {
        int row = wn + j * 16 + fm;
        bfr[j] = *(const bf16x8*)&Bs[row * 64 + ((((s << 2) | q) ^ (row & 7)) << 3)];
      }
#pragma unroll
      for (int i = 0; i < 4; ++i)
#pragma unroll
        for (int j = 0; j < 4; ++j)
          acc[i][j] = __builtin_amdgcn_mfma_f32_16x16x32_bf16(af[i], bfr[j], acc[i][j], 0, 0, 0);
    }
  }
}

// ---------------------------------------------------------------------------
// QKV projection + RoPE. A=xb[8192x1024], B=Wb[3072x1024]. Grid (bm=64, bn=24).
__global__ __launch_bounds__(256, 3) void qkv_rope_gemm(
    const unsigned short* __restrict__ A, const unsigned short* __restrict__ B,
    unsigned short* __restrict__ Qr, unsigned short* __restrict__ Kr,
    unsigned short* __restrict__ Vt) {
  __shared__ __align__(16) unsigned short As[BM * BK];
  __shared__ __align__(16) unsigned short Bs[BN * BK];
  const int tid = threadIdx.x, lane = tid & 63, wave = tid >> 6;
  const int bm = blockIdx.x, bn = blockIdx.y;
  const int m0 = bm * BM, n0 = bn * BN;
  const int wm = (wave >> 1) * 64, wn = (wave & 1) * 64;
  const int q = lane >> 4, fm = lane & 15;

  f32x4 acc[4][4];
#pragma unroll
  for (int i = 0; i < 4; ++i)
#pragma unroll
    for (int j = 0; j < 4; ++j) acc[i][j] = (f32x4)(0.f);

  gemm_body(A, B, As, Bs, 1024, 1024, m0, n0, 16, tid, lane, wave, acc);

  if (n0 < 2048) {
    // Q or K: RoPE (pair (2c,2c+1) in adjacent lanes), chained angle addition.
    const float NEG = -13.287712379549449f / 1024.f;  // -log2(1e4)/1024
    unsigned short* dst = (n0 < 1024) ? Qr : Kr;
    const int t00 = (m0 + wm + q * 4) & 2047;
#pragma unroll
    for (int j = 0; j < 4; ++j) {
      int c = (n0 & 1023) + wn + j * 16 + fm;
      float th = exp2f((float)(c & ~1) * NEG);
      float sgn = (c & 1) ? 1.f : -1.f;
      float ang0 = (float)t00 * th;
      float cb = __cosf(ang0), sb = __sinf(ang0);
      float c1 = __cosf(th), s1 = __sinf(th);
      float c16 = __cosf(16.f * th), s16 = __sinf(16.f * th);
#pragma unroll
      for (int i = 0; i < 4; ++i) {
        int gmB = m0 + wm + i * 16 + q * 4;
        float cr = cb, sr = sb;
#pragma unroll
        for (int r = 0; r < 4; ++r) {
          float v = acc[i][j][r];
          float p = __shfl_xor(v, 1);
          dst[(long)(gmB + r) * 1024 + c] = f2bf(v * cr + sgn * p * sr);
          float crn = cr * c1 - sr * s1;
          sr = sr * c1 + cr * s1;
          cr = crn;
        }
        float cbn = cb * c16 - sb * s16;
        sb = sb * c16 + cb * s16;
        cb = cbn;
      }
    }
  } else {
    // V: transpose to Vt[b][c][t]; 4 consecutive t per lane -> 8-B stores
    const int c0 = n0 - 2048;
#pragma unroll
    for (int j = 0; j < 4; ++j) {
      int c = c0 + wn + j * 16 + fm;
#pragma unroll
      for (int i = 0; i < 4; ++i) {
        int gmB = m0 + wm + i * 16 + q * 4;
        int b = gmB >> 11, t = gmB & 2047;
        ushort4 pk;
        pk.x = f2bf(acc[i][j][0]);
        pk.y = f2bf(acc[i][j][1]);
        pk.z = f2bf(acc[i][j][2]);
        pk.w = f2bf(acc[i][j][3]);
        *(ushort4*)&Vt[((long)b * 1024 + c) * 2048 + t] = pk;
      }
    }
  }
}

// ---------------------------------------------------------------------------
// E = exp(mask(Qr@Kr^T)/32) per batch (z), bf16, + rowsums. Compact triangular
// grid: 151 blocks/batch, decode (bm,bn) from linear idx (no no-op blocks).
__global__ __launch_bounds__(256, 3) void s_gemm(
    const unsigned short* __restrict__ Qr, const unsigned short* __restrict__ Kr,
    unsigned short* __restrict__ Sb, float* __restrict__ rowsums) {
  __shared__ __align__(16) unsigned short As[BM * BK];
  __shared__ __align__(16) unsigned short Bs[BN * BK];
  const int tid = threadIdx.x, lane = tid & 63, wave = tid >> 6;
  const int z = blockIdx.z;
  int idx = blockIdx.x, bm = 0;
#pragma unroll 1
  for (; bm < 16; ++bm) {  // counts per bm: min(bm+2,16); total 151
    int cnt = (bm + 2 > 16) ? 16 : bm + 2;
    if (idx < cnt) break;
    idx -= cnt;
  }
  const int bn = idx;
  const unsigned short* A = Qr + (long)z * 2048 * 1024;
  const unsigned short* B = Kr + (long)z * 2048 * 1024;
  unsigned short* S = Sb + (long)z * 2048 * 2048;
  float* rs = rowsums + (long)z * 2048;
  const int m0 = bm * BM, n0 = bn * BN;
  const int wm = (wave >> 1) * 64, wn = (wave & 1) * 64;
  const int q = lane >> 4, fm = lane & 15;

  f32x4 acc[4][4];
#pragma unroll
  for (int i = 0; i < 4; ++i)
#pragma unroll
    for (int j = 0; j < 4; ++j) acc[i][j] = (f32x4)(0.f);

  gemm_body(A, B, As, Bs, 1024, 1024, m0, n0, 16, tid, lane, wave, acc);

  // rowsum scratch overlays Bs (frag reads complete after the final barrier)
  float* rsum = (float*)Bs;
  __syncthreads();
  if (tid < 128) rsum[tid] = 0.f;
  __syncthreads();

#pragma unroll
  for (int i = 0; i < 4; ++i) {
    int gmB = m0 + wm + i * 16 + q * 4;
    float ps[4] = {0.f, 0.f, 0.f, 0.f};
#pragma unroll
    for (int j = 0; j < 4; ++j) {
      int gn = n0 + wn + j * 16 + fm;
#pragma unroll
      for (int r = 0; r < 4; ++r) {
        float e = (gn <= gmB + r + 1) ? __expf(acc[i][j][r] * 0.03125f) : 0.f;
        unsigned short h = f2bf(e);
        S[(long)(gmB + r) * 2048 + gn] = h;
        ps[r] += bf2f(h);  // sum the rounded value (matches stored E)
      }
    }
#pragma unroll
    for (int r = 0; r < 4; ++r) {
      float v = ps[r];
      v += __shfl_xor(v, 1);
      v += __shfl_xor(v, 2);
      v += __shfl_xor(v, 4);
      v += __shfl_xor(v, 8);
      if (fm == 0) atomicAdd(&rsum[wm + i * 16 + q * 4 + r], v);
    }
  }
  __syncthreads();
  if (tid < 128) atomicAdd(&rs[m0 + tid], rsum[tid]);
}

// ---------------------------------------------------------------------------
// out = (E @ Vt^T) / rowsum per batch (z), K-loop truncated causally.
// bm decode: z in {0,1} descending (diagonal first), z in {2,3} ASCENDING.
// Rationale: blocks i and i+256 co-reside on the same CU (XCD round-robin);
// complementary decode makes per-CU pair work ktiles(15-y)+ktiles(y)=35..36
// (const) instead of 2*ktiles(15-y) = 6..64 (diag CU was the makespan).
__global__ __launch_bounds__(256, 3) void pv_gemm(
    const unsigned short* __restrict__ Sb, const unsigned short* __restrict__ Vt,
    const float* __restrict__ rowsums, float* __restrict__ out, int b0) {
  __shared__ __align__(16) unsigned short As[BM * BK];
  __shared__ __align__(16) unsigned short Bs[BN * BK];
  const int tid = threadIdx.x, lane = tid & 63, wave = tid >> 6;
  const int z = blockIdx.z;
  const int bm = (z & 2) ? blockIdx.y : (15 - blockIdx.y);
  const int bn = blockIdx.x;
  const unsigned short* A = Sb + (long)z * 2048 * 2048;
  const unsigned short* B = Vt + (long)(b0 + z) * 1024 * 2048;
  const float* rs = rowsums + (long)(b0 + z) * 2048;
  float* C = out + (long)(b0 + z) * 2048 * 1024;
  int ktiles = 2 * bm + 3;  // keys valid up to q+1, q <= m0+127; BK=64
  if (ktiles > 32) ktiles = 32;
  const int m0 = bm * BM, n0 = bn * BN;
  const int wm = (wave >> 1) * 64, wn = (wave & 1) * 64;
  const int q = lane >> 4, fm = lane & 15;

  f32x4 acc[4][4];
#pragma unroll
  for (int i = 0; i < 4; ++i)
#pragma unroll
    for (int j = 0; j < 4; ++j) acc[i][j] = (f32x4)(0.f);

  gemm_body(A, B, As, Bs, 2048, 2048, m0, n0, ktiles, tid, lane, wave, acc);

#pragma unroll
  for (int i = 0; i < 4; ++i) {
    int gmB = m0 + wm + i * 16 + q * 4;
#pragma unroll
    for (int r = 0; r < 4; ++r) {
      float inv = 1.f / rs[gmB + r];
#pragma unroll
      for (int j = 0; j < 4; ++j) {
        int gn = n0 + wn + j * 16 + fm;
        C[(long)(gmB + r) * 1024 + gn] = acc[i][j][r] * inv;
      }
    }
  }
}

// ---------------------------------------------------------------------------
extern "C" void kernel_launch(void* const* d_in, const int* in_sizes, int n_in,
                              void* d_out, int out_size, void* d_ws, size_t ws_size,
                              hipStream_t stream) {
  const float* x = (const float*)d_in[0];
  const float* Wq = (const float*)d_in[1];
  const float* Wk = (const float*)d_in[2];
  const float* Wv = (const float*)d_in[3];
  float* out = (float*)d_out;

  // Layout: rowsums[32 KB] | Qr[16 MB] | Kr[16 MB] | Vt[16 MB] | xb[16 MB] |
  // Wb[6 MB]. E (bf16, 8 MB/batch) overlays xb/Wb (dead after qkv_rope_gemm).
  float* rowsums = (float*)d_ws;                      // [4][2048] fp32
  unsigned short* Qr = (unsigned short*)d_ws + 16384; // +32 KB
  unsigned short* Kr = Qr + (long)8192 * 1024;
  unsigned short* Vt = Kr + (long)8192 * 1024;        // [b][c][t]
  unsigned short* xb = Vt + (long)8192 * 1024;
  unsigned short* Wb = xb + (long)8192 * 1024;
  unsigned short* Sb = xb;                            // bf16 E, BCH x 2048 x 2048

  int BCH = 4;
  while (BCH > 1 && (size_t)32768 + (size_t)(48 + 8 * BCH) * 1024 * 1024 > ws_size)
    BCH >>= 1;

  cvt_all<<<11265, 256, 0, stream>>>((const float4*)x, (const float4*)Wq,
                                     (const float4*)Wk, (const float4*)Wv,
                                     (ushort4*)xb, (ushort4*)Wb, (float4*)rowsums);

  qkv_rope_gemm<<<dim3(64, 24), 256, 0, stream>>>(xb, Wb, Qr, Kr, Vt);

  for (int b0 = 0; b0 < 4; b0 += BCH) {
    s_gemm<<<dim3(151, 1, BCH), 256, 0, stream>>>(Qr + (long)b0 * 2048 * 1024,
                                                  Kr + (long)b0 * 2048 * 1024,
                                                  Sb, rowsums + (long)b0 * 2048);
    pv_gemm<<<dim3(8, 16, BCH), 256, 0, stream>>>(Sb, Vt, rowsums, out, b0);
  }
}

// Round 2
// 218.868 us; speedup vs baseline: 1.0475x; 1.0475x over previous
//
#include <hip/hip_runtime.h>

// ---------------------------------------------------------------------------
// RoPE attention: out = softmax(mask(RoPE(xWq^T) @ RoPE(xWk^T)^T / sqrt(d))) @ (xWv^T)
// B=4, T=2048, d=1024. fp32 in/out, bf16 MFMA internally.
// R13 -> R14: pv_gemm rebalance without a mapping bet. R13's complementary
// bm decode was NEUTRAL -> the i/i+256-same-CU model is dead. What stands:
// 512 blocks = 2/CU ALL co-resident => no dynamic slack + low occupancy.
// Changes (pv only, numerics bit-identical):
//  (1) tile 128x128 -> 64x128 (IM=2): per-block work variance /4, finer
//      causal truncation, LDS 24 KB;
//  (2) grid 8bn x 32bm' x 4z = 1024 blocks at 3/CU -> 768 resident + 256
//      queued => hardware tail balancing regardless of CU mapping;
//  (3) global long-first order: dim3(8*BCH, 32), bm' = 31-y => the 32
//      diagonal (32-ktile) blocks dispatch first across all (bn,z).
// gemm_body templated on frag counts <IM,JN>; qkv/s use <4,4> unchanged.
// Predicted: pv ~ -20us if pv was makespan-bound; total ~205us. absmax must
// stay 0.01171875 (same accumulation order).
// ---------------------------------------------------------------------------

typedef float f32x4 __attribute__((ext_vector_type(4)));
typedef __bf16 bf16x8 __attribute__((ext_vector_type(8)));

#define BM 128
#define BN 128
#define BK 64  // ushorts per LDS tile row; 128x64x2B = 16 KB per buffer

__device__ __forceinline__ unsigned short f2bf(float f) {
  union { float f; unsigned int u; } c; c.f = f;
  unsigned int u = c.u;
  u += 0x7fffu + ((u >> 16) & 1u);  // round-nearest-even
  return (unsigned short)(u >> 16);
}
__device__ __forceinline__ float bf2f(unsigned short h) {
  union { unsigned int u; float f; } c; c.u = ((unsigned int)h) << 16;
  return c.f;
}

__device__ __forceinline__ void async16(const unsigned short* gp, unsigned short* lp) {
  __builtin_amdgcn_global_load_lds(
      (const __attribute__((address_space(1))) void*)gp,
      (__attribute__((address_space(3))) void*)lp, 16, 0, 0);
}

// ---------------------------------------------------------------------------
// All fp32->bf16 casts in one kernel; last block zeroes rowsums.
__global__ __launch_bounds__(256) void cvt_all(
    const float4* __restrict__ x, const float4* __restrict__ wq,
    const float4* __restrict__ wk, const float4* __restrict__ wv,
    ushort4* __restrict__ xb, ushort4* __restrict__ wb,
    float4* __restrict__ rowsums) {
  int b = blockIdx.x, t = threadIdx.x;
  if (b == 11264) {  // zero rowsums: 4*2048 fp32 = 2048 float4
#pragma unroll
    for (int i = 0; i < 8; ++i) rowsums[i * 256 + t] = float4{0.f, 0.f, 0.f, 0.f};
    return;
  }
  const float4* src;
  ushort4* dst;
  long i;
  if (b < 8192) { src = x; dst = xb; i = (long)b * 256 + t; }
  else if (b < 9216) { src = wq; dst = wb; i = (long)(b - 8192) * 256 + t; }
  else if (b < 10240) { src = wk; dst = wb + 262144; i = (long)(b - 9216) * 256 + t; }
  else { src = wv; dst = wb + 524288; i = (long)(b - 10240) * 256 + t; }
  float4 v = src[i];
  ushort4 o;
  o.x = f2bf(v.x); o.y = f2bf(v.y); o.z = f2bf(v.z); o.w = f2bf(v.w);
  dst[i] = o;
}

// ---------------------------------------------------------------------------
// NT-GEMM K-loop, BK=64, single-buffer global_load_lds staging.
// C[m,n] = sum_k A[m,k]*B[n,k]. A-tile = IM*32 rows, B-tile = JN*32 rows,
// 4 waves (2x2); each wave IM*16 x JN*16 via 16x16x32 frags, two k-steps of
// 32 per LDS tile. LDS position f=p*256+tid (16-B units) holds row
// f>>3 = p*32+srow; staged chunk c = (tid&7)^(srow&7) is p-invariant
// ((p*32)%8==0) -> base pointers + uniform per-iter adds. XOR swizzle keeps
// the DMA's lane-contiguous LDS layout conflict-free for frag reads.
template <int IM, int JN>
__device__ __forceinline__ void gemm_body(
    const unsigned short* __restrict__ A, const unsigned short* __restrict__ B,
    unsigned short* As, unsigned short* Bs,
    int lda, int ldb, int m0, int n0, int ktiles,
    int tid, int lane, int wave, f32x4 (&acc)[IM][JN]) {
  const int wm = (wave >> 1) * (IM * 16);
  const int wn = (wave & 1) * (JN * 16);
  const int fm = lane & 15;
  const int q = lane >> 4;
  const int srow = tid >> 3;                 // 0..31
  const int c = (tid & 7) ^ (srow & 7);      // staged 16-B chunk (p-invariant)
  const unsigned short* Ab = A + (long)(m0 + srow) * lda + c * 8;
  const unsigned short* Bb = B + (long)(n0 + srow) * ldb + c * 8;
  unsigned short* ldA = As + tid * 8;
  unsigned short* ldB = Bs + tid * 8;

  for (int kt = 0; kt < ktiles; ++kt) {
    const long k0 = (long)kt * BK;
    __syncthreads();  // prior frag reads done before LDS overwrite
#pragma unroll
    for (int p = 0; p < IM; ++p)
      async16(Ab + (long)(p * 32) * lda + k0, ldA + p * 2048);
#pragma unroll
    for (int p = 0; p < JN; ++p)
      async16(Bb + (long)(p * 32) * ldb + k0, ldB + p * 2048);
    __syncthreads();  // compiler drains vmcnt(0): tiles ready

#pragma unroll
    for (int s = 0; s < 2; ++s) {  // two k-steps of 32
      bf16x8 af[IM], bfr[JN];
#pragma unroll
      for (int i = 0; i < IM; ++i) {
        int row = wm + i * 16 + fm;
        af[i] = *(const bf16x8*)&As[row * 64 + ((((s << 2) | q) ^ (row & 7)) << 3)];
      }
#pragma unroll
      for (int j = 0; j < JN; ++j) {
        int row = wn + j * 16 + fm;
        bfr[j] = *(const bf16x8*)&Bs[row * 64 + ((((s << 2) | q) ^ (row & 7)) << 3)];
      }
#pragma unroll
      for (int i = 0; i < IM; ++i)
#pragma unroll
        for (int j = 0; j < JN; ++j)
          acc[i][j] = __builtin_amdgcn_mfma_f32_16x16x32_bf16(af[i], bfr[j], acc[i][j], 0, 0, 0);
    }
  }
}

// ---------------------------------------------------------------------------
// QKV projection + RoPE. A=xb[8192x1024], B=Wb[3072x1024]. Grid (bm=64, bn=24).
__global__ __launch_bounds__(256, 3) void qkv_rope_gemm(
    const unsigned short* __restrict__ A, const unsigned short* __restrict__ B,
    unsigned short* __restrict__ Qr, unsigned short* __restrict__ Kr,
    unsigned short* __restrict__ Vt) {
  __shared__ __align__(16) unsigned short As[BM * BK];
  __shared__ __align__(16) unsigned short Bs[BN * BK];
  const int tid = threadIdx.x, lane = tid & 63, wave = tid >> 6;
  const int bm = blockIdx.x, bn = blockIdx.y;
  const int m0 = bm * BM, n0 = bn * BN;
  const int wm = (wave >> 1) * 64, wn = (wave & 1) * 64;
  const int q = lane >> 4, fm = lane & 15;

  f32x4 acc[4][4];
#pragma unroll
  for (int i = 0; i < 4; ++i)
#pragma unroll
    for (int j = 0; j < 4; ++j) acc[i][j] = (f32x4)(0.f);

  gemm_body<4, 4>(A, B, As, Bs, 1024, 1024, m0, n0, 16, tid, lane, wave, acc);

  if (n0 < 2048) {
    // Q or K: RoPE (pair (2c,2c+1) in adjacent lanes), chained angle addition.
    const float NEG = -13.287712379549449f / 1024.f;  // -log2(1e4)/1024
    unsigned short* dst = (n0 < 1024) ? Qr : Kr;
    const int t00 = (m0 + wm + q * 4) & 2047;
#pragma unroll
    for (int j = 0; j < 4; ++j) {
      int c = (n0 & 1023) + wn + j * 16 + fm;
      float th = exp2f((float)(c & ~1) * NEG);
      float sgn = (c & 1) ? 1.f : -1.f;
      float ang0 = (float)t00 * th;
      float cb = __cosf(ang0), sb = __sinf(ang0);
      float c1 = __cosf(th), s1 = __sinf(th);
      float c16 = __cosf(16.f * th), s16 = __sinf(16.f * th);
#pragma unroll
      for (int i = 0; i < 4; ++i) {
        int gmB = m0 + wm + i * 16 + q * 4;
        float cr = cb, sr = sb;
#pragma unroll
        for (int r = 0; r < 4; ++r) {
          float v = acc[i][j][r];
          float p = __shfl_xor(v, 1);
          dst[(long)(gmB + r) * 1024 + c] = f2bf(v * cr + sgn * p * sr);
          float crn = cr * c1 - sr * s1;
          sr = sr * c1 + cr * s1;
          cr = crn;
        }
        float cbn = cb * c16 - sb * s16;
        sb = sb * c16 + cb * s16;
        cb = cbn;
      }
    }
  } else {
    // V: transpose to Vt[b][c][t]; 4 consecutive t per lane -> 8-B stores
    const int c0 = n0 - 2048;
#pragma unroll
    for (int j = 0; j < 4; ++j) {
      int c = c0 + wn + j * 16 + fm;
#pragma unroll
      for (int i = 0; i < 4; ++i) {
        int gmB = m0 + wm + i * 16 + q * 4;
        int b = gmB >> 11, t = gmB & 2047;
        ushort4 pk;
        pk.x = f2bf(acc[i][j][0]);
        pk.y = f2bf(acc[i][j][1]);
        pk.z = f2bf(acc[i][j][2]);
        pk.w = f2bf(acc[i][j][3]);
        *(ushort4*)&Vt[((long)b * 1024 + c) * 2048 + t] = pk;
      }
    }
  }
}

// ---------------------------------------------------------------------------
// E = exp(mask(Qr@Kr^T)/32) per batch (z), bf16, + rowsums. Compact triangular
// grid: 151 blocks/batch, decode (bm,bn) from linear idx (no no-op blocks).
__global__ __launch_bounds__(256, 3) void s_gemm(
    const unsigned short* __restrict__ Qr, const unsigned short* __restrict__ Kr,
    unsigned short* __restrict__ Sb, float* __restrict__ rowsums) {
  __shared__ __align__(16) unsigned short As[BM * BK];
  __shared__ __align__(16) unsigned short Bs[BN * BK];
  const int tid = threadIdx.x, lane = tid & 63, wave = tid >> 6;
  const int z = blockIdx.z;
  int idx = blockIdx.x, bm = 0;
#pragma unroll 1
  for (; bm < 16; ++bm) {  // counts per bm: min(bm+2,16); total 151
    int cnt = (bm + 2 > 16) ? 16 : bm + 2;
    if (idx < cnt) break;
    idx -= cnt;
  }
  const int bn = idx;
  const unsigned short* A = Qr + (long)z * 2048 * 1024;
  const unsigned short* B = Kr + (long)z * 2048 * 1024;
  unsigned short* S = Sb + (long)z * 2048 * 2048;
  float* rs = rowsums + (long)z * 2048;
  const int m0 = bm * BM, n0 = bn * BN;
  const int wm = (wave >> 1) * 64, wn = (wave & 1) * 64;
  const int q = lane >> 4, fm = lane & 15;

  f32x4 acc[4][4];
#pragma unroll
  for (int i = 0; i < 4; ++i)
#pragma unroll
    for (int j = 0; j < 4; ++j) acc[i][j] = (f32x4)(0.f);

  gemm_body<4, 4>(A, B, As, Bs, 1024, 1024, m0, n0, 16, tid, lane, wave, acc);

  // rowsum scratch overlays Bs (frag reads complete after the final barrier)
  float* rsum = (float*)Bs;
  __syncthreads();
  if (tid < 128) rsum[tid] = 0.f;
  __syncthreads();

#pragma unroll
  for (int i = 0; i < 4; ++i) {
    int gmB = m0 + wm + i * 16 + q * 4;
    float ps[4] = {0.f, 0.f, 0.f, 0.f};
#pragma unroll
    for (int j = 0; j < 4; ++j) {
      int gn = n0 + wn + j * 16 + fm;
#pragma unroll
      for (int r = 0; r < 4; ++r) {
        float e = (gn <= gmB + r + 1) ? __expf(acc[i][j][r] * 0.03125f) : 0.f;
        unsigned short h = f2bf(e);
        S[(long)(gmB + r) * 2048 + gn] = h;
        ps[r] += bf2f(h);  // sum the rounded value (matches stored E)
      }
    }
#pragma unroll
    for (int r = 0; r < 4; ++r) {
      float v = ps[r];
      v += __shfl_xor(v, 1);
      v += __shfl_xor(v, 2);
      v += __shfl_xor(v, 4);
      v += __shfl_xor(v, 8);
      if (fm == 0) atomicAdd(&rsum[wm + i * 16 + q * 4 + r], v);
    }
  }
  __syncthreads();
  if (tid < 128) atomicAdd(&rs[m0 + tid], rsum[tid]);
}

// ---------------------------------------------------------------------------
// out = (E @ Vt^T) / rowsum per batch (z), K-loop truncated causally.
// Tile 64x128 (IM=2), grid dim3(8*BCH, 32): bn = x&7, z = x>>3, bm' = 31-y
// => global long-first dispatch (all 32-ktile diagonal blocks first), 1024
// blocks at 3/CU = 768 resident + 256 queued for dynamic tail balance.
__global__ __launch_bounds__(256, 3) void pv_gemm(
    const unsigned short* __restrict__ Sb, const unsigned short* __restrict__ Vt,
    const float* __restrict__ rowsums, float* __restrict__ out, int b0) {
  __shared__ __align__(16) unsigned short As[64 * BK];
  __shared__ __align__(16) unsigned short Bs[128 * BK];
  const int tid = threadIdx.x, lane = tid & 63, wave = tid >> 6;
  const int bn = blockIdx.x & 7;
  const int z = blockIdx.x >> 3;
  const int bm = 31 - blockIdx.y;  // 64-row granularity, longest-K first
  const unsigned short* A = Sb + (long)z * 2048 * 2048;
  const unsigned short* B = Vt + (long)(b0 + z) * 1024 * 2048;
  const float* rs = rowsums + (long)(b0 + z) * 2048;
  float* C = out + (long)(b0 + z) * 2048 * 1024;
  int ktiles = bm + 2;  // keys valid up to q+1, q <= m0+63; BK=64
  if (ktiles > 32) ktiles = 32;
  const int m0 = bm * 64, n0 = bn * 128;
  const int wm = (wave >> 1) * 32, wn = (wave & 1) * 64;
  const int q = lane >> 4, fm = lane & 15;

  f32x4 acc[2][4];
#pragma unroll
  for (int i = 0; i < 2; ++i)
#pragma unroll
    for (int j = 0; j < 4; ++j) acc[i][j] = (f32x4)(0.f);

  gemm_body<2, 4>(A, B, As, Bs, 2048, 2048, m0, n0, ktiles, tid, lane, wave, acc);

#pragma unroll
  for (int i = 0; i < 2; ++i) {
    int gmB = m0 + wm + i * 16 + q * 4;
#pragma unroll
    for (int r = 0; r < 4; ++r) {
      float inv = 1.f / rs[gmB + r];
#pragma unroll
      for (int j = 0; j < 4; ++j) {
        int gn = n0 + wn + j * 16 + fm;
        C[(long)(gmB + r) * 1024 + gn] = acc[i][j][r] * inv;
      }
    }
  }
}

// ---------------------------------------------------------------------------
extern "C" void kernel_launch(void* const* d_in, const int* in_sizes, int n_in,
                              void* d_out, int out_size, void* d_ws, size_t ws_size,
                              hipStream_t stream) {
  const float* x = (const float*)d_in[0];
  const float* Wq = (const float*)d_in[1];
  const float* Wk = (const float*)d_in[2];
  const float* Wv = (const float*)d_in[3];
  float* out = (float*)d_out;

  // Layout: rowsums[32 KB] | Qr[16 MB] | Kr[16 MB] | Vt[16 MB] | xb[16 MB] |
  // Wb[6 MB]. E (bf16, 8 MB/batch) overlays xb/Wb (dead after qkv_rope_gemm).
  float* rowsums = (float*)d_ws;                      // [4][2048] fp32
  unsigned short* Qr = (unsigned short*)d_ws + 16384; // +32 KB
  unsigned short* Kr = Qr + (long)8192 * 1024;
  unsigned short* Vt = Kr + (long)8192 * 1024;        // [b][c][t]
  unsigned short* xb = Vt + (long)8192 * 1024;
  unsigned short* Wb = xb + (long)8192 * 1024;
  unsigned short* Sb = xb;                            // bf16 E, BCH x 2048 x 2048

  int BCH = 4;
  while (BCH > 1 && (size_t)32768 + (size_t)(48 + 8 * BCH) * 1024 * 1024 > ws_size)
    BCH >>= 1;

  cvt_all<<<11265, 256, 0, stream>>>((const float4*)x, (const float4*)Wq,
                                     (const float4*)Wk, (const float4*)Wv,
                                     (ushort4*)xb, (ushort4*)Wb, (float4*)rowsums);

  qkv_rope_gemm<<<dim3(64, 24), 256, 0, stream>>>(xb, Wb, Qr, Kr, Vt);

  for (int b0 = 0; b0 < 4; b0 += BCH) {
    s_gemm<<<dim3(151, 1, BCH), 256, 0, stream>>>(Qr + (long)b0 * 2048 * 1024,
                                                  Kr + (long)b0 * 2048 * 1024,
                                                  Sb, rowsums + (long)b0 * 2048);
    pv_gemm<<<dim3(8 * BCH, 32), 256, 0, stream>>>(Sb, Vt, rowsums, out, b0);
  }
}